// Round 6
// baseline (710.543 us; speedup 1.0000x reference)
//
#include <hip/hip_runtime.h>
#include <hip/hip_bf16.h>
#include <hip/hip_fp16.h>

constexpr int FDIM = 128;
#define HSCALE 16384.0f         // 2^14: |h|<1 -> scaled <16384 <= 65504, always safe
#define HSCALE_INV (1.0f/16384.0f)

typedef _Float16 f16x8 __attribute__((ext_vector_type(8)));
typedef float f32x4 __attribute__((ext_vector_type(4)));

// ===================== atomic-free CSR build: 3-level MSD partition =====================
// record: [col:17 @47][row:17 @30][ew_f16 @0]   (col < 2^17 required; N=100000 ok)
constexpr int CHUNK = 4096;
constexpr int B1 = 64;
constexpr int B2 = 64;
constexpr int NC2 = 64;
constexpr int MAXC2 = 20;

__global__ __launch_bounds__(256) void k_p1hist(const int* __restrict__ col,
                                                int* __restrict__ cnt1, int E, int NB1)
{
    __shared__ int h[B1];
    int blk = blockIdx.x, t = threadIdx.x;
    if (t < B1) h[t] = 0;
    __syncthreads();
    int base = blk * CHUNK;
    for (int i = t; i < CHUNK; i += 256) {
        int g = base + i;
        if (g < E) atomicAdd(&h[col[g] >> 11], 1);
    }
    __syncthreads();
    if (t < B1) cnt1[t * NB1 + blk] = h[t];
}

__global__ __launch_bounds__(256) void k_blocksum(const int* __restrict__ cnt,
                                                  int* __restrict__ bsum, int n)
{
    __shared__ int s[256];
    int t = threadIdx.x;
    int i = blockIdx.x * 256 + t;
    s[t] = (i < n) ? cnt[i] : 0;
    __syncthreads();
    for (int o = 128; o > 0; o >>= 1) {
        if (t < o) s[t] += s[t + o];
        __syncthreads();
    }
    if (t == 0) bsum[blockIdx.x] = s[0];
}

__global__ __launch_bounds__(1024) void k_scan_bsum(const int* __restrict__ bsum,
                                                    int* __restrict__ boff, int nb,
                                                    int* __restrict__ out, int n, int total)
{
    __shared__ int s[1024];
    int t = threadIdx.x;
    int v = (t < nb) ? bsum[t] : 0;
    s[t] = v;
    __syncthreads();
    for (int o = 1; o < 1024; o <<= 1) {
        int u = (t >= o) ? s[t - o] : 0;
        __syncthreads();
        s[t] += u;
        __syncthreads();
    }
    if (t < nb) boff[t] = s[t] - v;   // exclusive
    if (t == 0) out[n] = total;
}

__global__ __launch_bounds__(256) void k_offsets(const int* __restrict__ cnt,
                                                 const int* __restrict__ boff,
                                                 int* __restrict__ out, int n)
{
    __shared__ int s[256];
    int t = threadIdx.x;
    int i = blockIdx.x * 256 + t;
    int v = (i < n) ? cnt[i] : 0;
    s[t] = v;
    __syncthreads();
    for (int o = 1; o < 256; o <<= 1) {
        int u = (t >= o) ? s[t - o] : 0;
        __syncthreads();
        s[t] += u;
        __syncthreads();
    }
    if (i < n) out[i] = boff[blockIdx.x] + s[t] - v;
}

__global__ __launch_bounds__(256) void k_p1part(const int* __restrict__ col,
                                                const int* __restrict__ row,
                                                const float* __restrict__ ew,
                                                const int* __restrict__ cnt1,
                                                const int* __restrict__ scan1,
                                                unsigned long long* __restrict__ rec1,
                                                int E, int NB1)
{
    __shared__ unsigned long long stage[CHUNK];
    __shared__ int hcnt[B1], lb[B1], gb[B1], cur[B1];
    int blk = blockIdx.x, t = threadIdx.x;
    if (t < B1) {
        hcnt[t] = cnt1[t * NB1 + blk];
        gb[t]   = scan1[t * NB1 + blk];
    }
    __syncthreads();
    if (t == 0) {
        int run = 0;
        for (int b = 0; b < B1; ++b) { lb[b] = run; run += hcnt[b]; }
    }
    __syncthreads();
    if (t < B1) cur[t] = lb[t];
    __syncthreads();
    int base = blk * CHUNK;
    for (int i = t; i < CHUNK; i += 256) {
        int g = base + i;
        if (g < E) {
            int c = col[g], r = row[g];
            unsigned long long rc = ((unsigned long long)c << 47) |
                                    ((unsigned long long)r << 30) |
                                    (unsigned long long)__half_as_ushort(__float2half(ew[g]));
            int p = atomicAdd(&cur[c >> 11], 1);
            stage[p] = rc;
        }
    }
    __syncthreads();
    int here = min(CHUNK, E - base);
    for (int j = t; j < here; j += 256) {
        unsigned long long rc = stage[j];
        int b = (int)(rc >> 58);
        rec1[gb[b] + (j - lb[b])] = rc;
    }
}

__global__ __launch_bounds__(256) void k_p2hist(const unsigned long long* __restrict__ rec1,
                                                const int* __restrict__ scan1,
                                                int* __restrict__ cnt2, int NB1)
{
    __shared__ int h[B2];
    int b = blockIdx.x / MAXC2, ci = blockIdx.x % MAXC2, t = threadIdx.x;
    int S1 = scan1[b * NB1];
    int S2 = scan1[(b + 1) * NB1];
    int size = S2 - S1;
    for (int c = ci; c * CHUNK < size && c < NC2; c += MAXC2) {
        __syncthreads();
        if (t < B2) h[t] = 0;
        __syncthreads();
        int cb = S1 + c * CHUNK, ce = min(cb + CHUNK, S2);
        for (int i = cb + t; i < ce; i += 256)
            atomicAdd(&h[(int)((rec1[i] >> 52) & 63)], 1);
        __syncthreads();
        if (t < B2) cnt2[(b * B2 + t) * NC2 + c] = h[t];
    }
}

__global__ __launch_bounds__(256) void k_p2part(const unsigned long long* __restrict__ rec1,
                                                const int* __restrict__ scan1,
                                                const int* __restrict__ cnt2,
                                                const int* __restrict__ scan2,
                                                unsigned long long* __restrict__ rec2, int NB1)
{
    __shared__ unsigned long long stage[CHUNK];
    __shared__ int hcnt[B2], lb[B2], gb[B2], cur[B2];
    int b = blockIdx.x / MAXC2, ci = blockIdx.x % MAXC2, t = threadIdx.x;
    int S1 = scan1[b * NB1];
    int S2 = scan1[(b + 1) * NB1];
    int size = S2 - S1;
    for (int c = ci; c * CHUNK < size && c < NC2; c += MAXC2) {
        __syncthreads();
        if (t < B2) {
            hcnt[t] = cnt2[(b * B2 + t) * NC2 + c];
            gb[t]   = scan2[(b * B2 + t) * NC2 + c];
        }
        __syncthreads();
        if (t == 0) {
            int run = 0;
            for (int sb = 0; sb < B2; ++sb) { lb[sb] = run; run += hcnt[sb]; }
        }
        __syncthreads();
        if (t < B2) cur[t] = lb[t];
        __syncthreads();
        int cb = S1 + c * CHUNK, ce = min(cb + CHUNK, S2);
        for (int i = cb + t; i < ce; i += 256) {
            unsigned long long rc = rec1[i];
            int p = atomicAdd(&cur[(int)((rc >> 52) & 63)], 1);
            stage[p] = rc;
        }
        __syncthreads();
        int here = ce - cb;
        for (int j = t; j < here; j += 256) {
            unsigned long long rc = stage[j];
            int sb = (int)((rc >> 52) & 63);
            rec2[gb[sb] + (j - lb[sb])] = rc;
        }
    }
}

// final: counting sort per 32-node sub-bucket; emits ep=(row, ew_f32), off, deg
__global__ __launch_bounds__(256) void k_p3(const unsigned long long* __restrict__ rec2,
                                            const int* __restrict__ scan2,
                                            int2* __restrict__ ep, int* __restrict__ off,
                                            float* __restrict__ deg, int N, int E)
{
    __shared__ int h[32], lb[32], cur[32];
    __shared__ float dg[32];
    int g = blockIdx.x, t = threadIdx.x;
    int S1 = scan2[g * NC2];
    int S2 = scan2[(g + 1) * NC2];
    if (t < 32) { h[t] = 0; dg[t] = 0.f; }
    __syncthreads();
    for (int i = S1 + t; i < S2; i += 256) {
        unsigned long long rc = rec2[i];
        int nl = (int)((rc >> 47) & 31);
        atomicAdd(&h[nl], 1);
        atomicAdd(&dg[nl], __half2float(__ushort_as_half((unsigned short)(rc & 0xFFFF))));
    }
    __syncthreads();
    if (t == 0) {
        int run = S1;
        for (int k = 0; k < 32; ++k) { lb[k] = run; run += h[k]; }
    }
    __syncthreads();
    if (t < 32) {
        cur[t] = lb[t];
        int node = g * 32 + t;
        if (node < N) { off[node] = lb[t]; deg[node] = dg[t]; }
    }
    if (g == 0 && t == 0) off[N] = E;
    __syncthreads();
    for (int i = S1 + t; i < S2; i += 256) {
        unsigned long long rc = rec2[i];
        int nl = (int)((rc >> 47) & 31);
        int p = atomicAdd(&cur[nl], 1);
        float w = __half2float(__ushort_as_half((unsigned short)(rc & 0xFFFF)));
        ep[p] = make_int2((int)((rc >> 30) & 0x1FFFF), __float_as_int(w));
    }
}

__global__ __launch_bounds__(256) void k_dis(const float* __restrict__ deg,
                                             float* __restrict__ dis, int N)
{
    int i = blockIdx.x * 256 + threadIdx.x;
    if (i >= N) return;
    float d = deg[i] + 1.0f;                  // self-loop; d >= 1 always
    dis[i] = 1.0f / sqrtf(d);
}

// patch ep.y: ew -> norm = dis[row]*ew*dis[col]
__global__ __launch_bounds__(256) void k_norm(int2* __restrict__ ep,
                                              const int* __restrict__ off,
                                              const float* __restrict__ dis, int n)
{
    int gt = blockIdx.x * 256 + threadIdx.x;
    int node = gt >> 6;
    int lane = threadIdx.x & 63;
    if (node >= n) return;
    float dc = dis[node];
    int e1 = off[node + 1];
    for (int e = off[node] + lane; e < e1; e += 64) {
        int2 p = ep[e];
        ep[e] = make_int2(p.x, __float_as_int(dis[p.x] * __int_as_float(p.y) * dc));
    }
}

// ---------------- f32 -> f16 convert (stage A input) ----------------
__global__ __launch_bounds__(256) void k_cvt(const float4* __restrict__ in,
                                             __half2* __restrict__ out, int n4)
{
    int i = blockIdx.x * 256 + threadIdx.x;
    if (i >= n4) return;
    float4 v = in[i];
    __half2 a = __floats2half2_rn(v.x, v.y);
    __half2 b = __floats2half2_rn(v.z, v.w);
    float2 pk;
    ((__half2*)&pk)[0] = a;
    ((__half2*)&pk)[1] = b;
    *(float2*)&out[(size_t)i * 2] = pk;
}

// ---------------- W (f32 [128][N]) -> Wt (f16 [N][128]) transpose ----------------
__global__ __launch_bounds__(256) void k_wt(const float* __restrict__ W,
                                            __half* __restrict__ Wt, int N)
{
    int idx = blockIdx.x * 256 + threadIdx.x;
    if (idx >= N * 128) return;
    int n = idx >> 7, k = idx & 127;
    Wt[idx] = __float2half(W[(size_t)k * N + n]);
}

// ---------------- SpMM: Yh = fp16(A_hat @ X) ----------------
// one wave per node; 8-wide batches, 2-deep gather pipeline, ep prefetched
// one batch further. 32-bit offset addressing (table < 4 GB).
__global__ __launch_bounds__(256) void k_spmm(const __half2* __restrict__ Xh,
                                              const int2* __restrict__ ep,
                                              const int* __restrict__ off,
                                              const float* __restrict__ dis,
                                              __half2* __restrict__ Yh, int n)
{
    int gt = blockIdx.x * 256 + threadIdx.x;
    int node = gt >> 6;
    int lane = threadIdx.x & 63;
    if (node >= n) return;

    const char* Xb = (const char*)Xh;
    const unsigned loff = (unsigned)lane << 2;

    float s = dis[node];
    float sn = s * s;                       // self-loop norm
    float2 x0 = __half22float2(*(const __half2*)(Xb + (((unsigned)node << 8) + loff)));
    float2 ac0, ac1, ac2, ac3;
    ac0.x = sn * x0.x; ac0.y = sn * x0.y;
    ac1.x = 0.f; ac1.y = 0.f;
    ac2.x = 0.f; ac2.y = 0.f;
    ac3.x = 0.f; ac3.y = 0.f;

    const int e0 = off[node];
    const int cnt = off[node + 1] - e0;
    const int2* el = ep + e0;
    const int nb = cnt >> 3;
    int done = 0;

    if (nb >= 2) {
        int2 epn[8];
        __half2 xc[8], xn[8];
        float wc[8], wn[8];
        // prolog: batch 0 -> xc/wc (gathers issued), batch 1 edges -> epn
        {
            int2 epc[8];
            #pragma unroll
            for (int i = 0; i < 8; ++i) epc[i] = el[i];
            #pragma unroll
            for (int i = 0; i < 8; ++i)
                xc[i] = *(const __half2*)(Xb + (((unsigned)epc[i].x << 8) + loff));
            #pragma unroll
            for (int i = 0; i < 8; ++i) wc[i] = __int_as_float(epc[i].y);
        }
        #pragma unroll
        for (int i = 0; i < 8; ++i) epn[i] = el[8 + i];

        #pragma unroll 2
        for (int b = 0; b + 2 < nb; ++b) {
            // issue gathers for batch b+1
            #pragma unroll
            for (int i = 0; i < 8; ++i)
                xn[i] = *(const __half2*)(Xb + (((unsigned)epn[i].x << 8) + loff));
            #pragma unroll
            for (int i = 0; i < 8; ++i) wn[i] = __int_as_float(epn[i].y);
            // prefetch edges for batch b+2 (latency covered by compute below)
            const int2* eb = el + (size_t)(b + 2) * 8;
            #pragma unroll
            for (int i = 0; i < 8; ++i) epn[i] = eb[i];
            // compute batch b
            {
                float2 f0 = __half22float2(xc[0]), f1 = __half22float2(xc[1]);
                float2 f2 = __half22float2(xc[2]), f3 = __half22float2(xc[3]);
                float2 f4 = __half22float2(xc[4]), f5 = __half22float2(xc[5]);
                float2 f6 = __half22float2(xc[6]), f7 = __half22float2(xc[7]);
                ac0.x += wc[0] * f0.x; ac0.y += wc[0] * f0.y;
                ac1.x += wc[1] * f1.x; ac1.y += wc[1] * f1.y;
                ac2.x += wc[2] * f2.x; ac2.y += wc[2] * f2.y;
                ac3.x += wc[3] * f3.x; ac3.y += wc[3] * f3.y;
                ac0.x += wc[4] * f4.x; ac0.y += wc[4] * f4.y;
                ac1.x += wc[5] * f5.x; ac1.y += wc[5] * f5.y;
                ac2.x += wc[6] * f6.x; ac2.y += wc[6] * f6.y;
                ac3.x += wc[7] * f7.x; ac3.y += wc[7] * f7.y;
            }
            // rotate (renamed away by unroll 2)
            #pragma unroll
            for (int i = 0; i < 8; ++i) { xc[i] = xn[i]; wc[i] = wn[i]; }
        }
        // epilogue: compute batch nb-2 (in xc), then batch nb-1 (edges in epn)
        #pragma unroll
        for (int i = 0; i < 8; ++i)
            xn[i] = *(const __half2*)(Xb + (((unsigned)epn[i].x << 8) + loff));
        #pragma unroll
        for (int i = 0; i < 8; ++i) wn[i] = __int_as_float(epn[i].y);
        {
            float2 f0 = __half22float2(xc[0]), f1 = __half22float2(xc[1]);
            float2 f2 = __half22float2(xc[2]), f3 = __half22float2(xc[3]);
            float2 f4 = __half22float2(xc[4]), f5 = __half22float2(xc[5]);
            float2 f6 = __half22float2(xc[6]), f7 = __half22float2(xc[7]);
            ac0.x += wc[0] * f0.x; ac0.y += wc[0] * f0.y;
            ac1.x += wc[1] * f1.x; ac1.y += wc[1] * f1.y;
            ac2.x += wc[2] * f2.x; ac2.y += wc[2] * f2.y;
            ac3.x += wc[3] * f3.x; ac3.y += wc[3] * f3.y;
            ac0.x += wc[4] * f4.x; ac0.y += wc[4] * f4.y;
            ac1.x += wc[5] * f5.x; ac1.y += wc[5] * f5.y;
            ac2.x += wc[6] * f6.x; ac2.y += wc[6] * f6.y;
            ac3.x += wc[7] * f7.x; ac3.y += wc[7] * f7.y;
        }
        {
            float2 f0 = __half22float2(xn[0]), f1 = __half22float2(xn[1]);
            float2 f2 = __half22float2(xn[2]), f3 = __half22float2(xn[3]);
            float2 f4 = __half22float2(xn[4]), f5 = __half22float2(xn[5]);
            float2 f6 = __half22float2(xn[6]), f7 = __half22float2(xn[7]);
            ac0.x += wn[0] * f0.x; ac0.y += wn[0] * f0.y;
            ac1.x += wn[1] * f1.x; ac1.y += wn[1] * f1.y;
            ac2.x += wn[2] * f2.x; ac2.y += wn[2] * f2.y;
            ac3.x += wn[3] * f3.x; ac3.y += wn[3] * f3.y;
            ac0.x += wn[4] * f4.x; ac0.y += wn[4] * f4.y;
            ac1.x += wn[5] * f5.x; ac1.y += wn[5] * f5.y;
            ac2.x += wn[6] * f6.x; ac2.y += wn[6] * f6.y;
            ac3.x += wn[7] * f7.x; ac3.y += wn[7] * f7.y;
        }
        done = nb * 8;
    }
    for (int e = done; e < cnt; ++e) {
        int2 p = el[e];
        float2 xv = __half22float2(*(const __half2*)(Xb + (((unsigned)p.x << 8) + loff)));
        float w = __int_as_float(p.y);
        ac0.x += w * xv.x; ac0.y += w * xv.y;
    }
    float rx = (ac0.x + ac1.x) + (ac2.x + ac3.x);
    float ry = (ac0.y + ac1.y) + (ac2.y + ac3.y);
    Yh[(size_t)node * 64 + lane] = __floats2half2_rn(rx, ry);
}

// fast tanh: 1 - 2/(e^{2x}+1) via v_exp + v_rcp
__device__ __forceinline__ float fast_tanh(float x) {
    float e = __expf(2.0f * x);
    return 1.0f - 2.0f * __builtin_amdgcn_rcpf(e + 1.0f);
}

// ---------------- MFMA GEMM: prod_{w<NW} tanh(IS*(Yh @ W_w) + b_w) ----------------
template <int FOUT, int NW, bool PRECISE, bool HOUT>
__global__ __launch_bounds__(256, 4) void k_mgemm(const __half* __restrict__ Yh,
                                                  float IS, float OS,
                                                  const __half* __restrict__ Wt0, const float* __restrict__ B0,
                                                  const __half* __restrict__ Wt1, const float* __restrict__ B1,
                                                  const __half* __restrict__ Wt2, const float* __restrict__ B2,
                                                  void* __restrict__ Outv, int nRows)
{
    constexpr int NF = FOUT / 16;
    int tid = threadIdx.x;
    int wv = tid >> 6;
    int lane = tid & 63;
    int lo = lane & 15, hi = lane >> 4;
    int r0 = blockIdx.x * 64 + wv * 16;

    f16x8 a[4];
    {
        int row = r0 + lo;
        if (row >= nRows) row = nRows - 1;
        const __half* Ap = Yh + (size_t)row * 128 + hi * 8;
        #pragma unroll
        for (int ks = 0; ks < 4; ++ks)
            a[ks] = *(const f16x8*)(Ap + ks * 32);
    }

    const __half* Wts[3] = {Wt0, Wt1, Wt2};
    const float*  Bs[3]  = {B0, B1, B2};
    float prod[NF][4];

    #pragma unroll
    for (int w = 0; w < NW; ++w) {
        const __half* Wt = Wts[w] + (size_t)lo * 128 + hi * 8;
        const float*  Bb = Bs[w];
        #pragma unroll
        for (int f = 0; f < NF; ++f) {
            const __half* Bp = Wt + (size_t)f * 16 * 128;
            f32x4 acc = {0.f, 0.f, 0.f, 0.f};
            #pragma unroll
            for (int ks = 0; ks < 4; ++ks) {
                f16x8 bfrag = *(const f16x8*)(Bp + ks * 32);
                acc = __builtin_amdgcn_mfma_f32_16x16x32_f16(a[ks], bfrag, acc, 0, 0, 0);
            }
            float bias = Bb[f * 16 + lo];
            #pragma unroll
            for (int r = 0; r < 4; ++r) {
                float pre = fmaf(acc[r], IS, bias);
                float t = PRECISE ? tanhf(pre) : fast_tanh(pre);
                prod[f][r] = (w == 0) ? t : prod[f][r] * t;
            }
        }
    }

    #pragma unroll
    for (int f = 0; f < NF; ++f) {
        int c = f * 16 + lo;
        #pragma unroll
        for (int r = 0; r < 4; ++r) {
            int row = r0 + hi * 4 + r;
            if (row < nRows) {
                if constexpr (HOUT)
                    ((__half*)Outv)[(size_t)row * FOUT + c] = __float2half(prod[f][r] * OS);
                else
                    ((float*)Outv)[(size_t)row * FOUT + c] = prod[f][r] * OS;
            }
        }
    }
}

extern "C" void kernel_launch(void* const* d_in, const int* in_sizes, int n_in,
                              void* d_out, int out_size, void* d_ws, size_t ws_size,
                              hipStream_t stream)
{
    const float* h0 = (const float*)d_in[0];
    const int*   ei = (const int*)d_in[1];
    const float* ew = (const float*)d_in[2];
    const float* W1 = (const float*)d_in[3];  const float* b1 = (const float*)d_in[4];
    const float* W2 = (const float*)d_in[5];  const float* b2 = (const float*)d_in[6];
    const float* W3 = (const float*)d_in[7];  const float* b3 = (const float*)d_in[8];
    const float* W4 = (const float*)d_in[9];  const float* b4 = (const float*)d_in[10];
    const float* W5 = (const float*)d_in[11]; const float* b5 = (const float*)d_in[12];
    const float* W6 = (const float*)d_in[13]; const float* b6 = (const float*)d_in[14];

    const int N = in_sizes[0] / FDIM;
    const int E = in_sizes[2];
    const int* rowp = ei;
    const int* colp = ei + E;

    const int NB1 = (E + CHUNK - 1) / CHUNK;
    const int n1  = B1 * NB1;
    const int n2  = B1 * B2 * NC2;
    const int NBs1 = (n1 + 255) / 256;
    const int NBs2 = (n2 + 255) / 256;

    char* p = (char*)d_ws;
    auto alloc = [&](size_t bytes) -> void* {
        void* r = (void*)p;
        p += (bytes + 255) & ~(size_t)255;
        return r;
    };
    int* cnt1  = (int*)alloc((size_t)(n1 + 1) * 4);
    int* scan1 = (int*)alloc((size_t)(n1 + 1) * 4);
    int* cnt2  = (int*)alloc((size_t)(n2 + 1) * 4);
    int* scan2 = (int*)alloc((size_t)(n2 + 1) * 4);
    int* bsum  = (int*)alloc((size_t)1024 * 4);
    int* boff  = (int*)alloc((size_t)1024 * 4);
    int* off   = (int*)alloc((size_t)(N + 1) * 4);
    float* deg = (float*)alloc((size_t)N * 4);
    float* dis = (float*)alloc((size_t)N * 4);
    unsigned long long* rec1 = (unsigned long long*)alloc((size_t)E * 8);  // aliased by ep
    unsigned long long* rec2 = (unsigned long long*)alloc((size_t)E * 8);  // aliased by Yh
    __half2* Xh = (__half2*)alloc((size_t)N * FDIM * 2);
    __half2* Hh = (__half2*)alloc((size_t)N * FDIM * 2);
    __half* W1t = (__half*)alloc((size_t)128 * 128 * 2);
    __half* W2t = (__half*)alloc((size_t)128 * 128 * 2);
    __half* W3t = (__half*)alloc((size_t)128 * 128 * 2);
    __half* W4t = (__half*)alloc((size_t)128 * 128 * 2);
    __half* W5t = (__half*)alloc((size_t)128 * 128 * 2);
    __half* W6t = (__half*)alloc((size_t)64 * 128 * 2);

    int2*    ep = (int2*)rec1;       // rec1 dead after k_p2part
    __half2* Yh = (__half2*)rec2;    // rec2 dead after k_p3

    hipMemsetAsync(cnt2, 0, (size_t)(n2 + 1) * 4, stream);

    // ---- build ----
    k_p1hist<<<NB1, 256, 0, stream>>>(colp, cnt1, E, NB1);
    k_blocksum<<<NBs1, 256, 0, stream>>>(cnt1, bsum, n1);
    k_scan_bsum<<<1, 1024, 0, stream>>>(bsum, boff, NBs1, scan1, n1, E);
    k_offsets<<<NBs1, 256, 0, stream>>>(cnt1, boff, scan1, n1);
    k_p1part<<<NB1, 256, 0, stream>>>(colp, rowp, ew, cnt1, scan1, rec1, E, NB1);
    k_p2hist<<<B1 * MAXC2, 256, 0, stream>>>(rec1, scan1, cnt2, NB1);
    k_blocksum<<<NBs2, 256, 0, stream>>>(cnt2, bsum, n2);
    k_scan_bsum<<<1, 1024, 0, stream>>>(bsum, boff, NBs2, scan2, n2, E);
    k_offsets<<<NBs2, 256, 0, stream>>>(cnt2, boff, scan2, n2);
    k_p2part<<<B1 * MAXC2, 256, 0, stream>>>(rec1, scan1, cnt2, scan2, rec2, NB1);
    k_p3<<<B1 * B2, 256, 0, stream>>>(rec2, scan2, ep, off, deg, N, E);
    const int NBn = (N + 255) / 256;
    k_dis<<<NBn, 256, 0, stream>>>(deg, dis, N);
    const int sb = (N + 3) / 4;
    k_norm<<<sb, 256, 0, stream>>>(ep, off, dis, N);

    // ---- dense prep ----
    k_cvt<<<(N * 32 + 255) / 256, 256, 0, stream>>>((const float4*)h0, Xh, N * 32);
    k_wt<<<64, 256, 0, stream>>>(W1, W1t, 128);
    k_wt<<<64, 256, 0, stream>>>(W2, W2t, 128);
    k_wt<<<64, 256, 0, stream>>>(W3, W3t, 128);
    k_wt<<<64, 256, 0, stream>>>(W4, W4t, 128);
    k_wt<<<64, 256, 0, stream>>>(W5, W5t, 128);
    k_wt<<<32, 256, 0, stream>>>(W6, W6t, 64);

    const int gb = (N + 63) / 64;

    // Stage A
    k_spmm<<<sb, 256, 0, stream>>>(Xh, ep, off, dis, Yh, N);
    k_mgemm<128, 3, false, true><<<gb, 256, 0, stream>>>((const __half*)Yh, 1.0f, HSCALE,
        W1t, b1, W2t, b2, W3t, b3, Hh, N);
    // Stage B
    k_spmm<<<sb, 256, 0, stream>>>(Hh, ep, off, dis, Yh, N);
    k_mgemm<128, 2, false, true><<<gb, 256, 0, stream>>>((const __half*)Yh, HSCALE_INV, HSCALE,
        W4t, b4, W5t, b5, nullptr, nullptr, Hh, N);
    // Stage C
    k_spmm<<<sb, 256, 0, stream>>>(Hh, ep, off, dis, Yh, N);
    k_mgemm<64, 1, true, false><<<gb, 256, 0, stream>>>((const __half*)Yh, HSCALE_INV, 1.0f,
        W6t, b6, nullptr, nullptr, nullptr, nullptr, d_out, N);
}

// Round 7
// 606.904 us; speedup vs baseline: 1.1708x; 1.1708x over previous
//
#include <hip/hip_runtime.h>
#include <hip/hip_bf16.h>
#include <hip/hip_fp16.h>

constexpr int FDIM = 128;
#define HSCALE 16384.0f         // 2^14: |h|<1 -> scaled <16384 <= 65504, always safe
#define HSCALE_INV (1.0f/16384.0f)
#define ZSCALE 0.125f           // extra headroom for Zh = Hh @ W6
#define ZSCALE_COMP (HSCALE_INV * 8.0f)

typedef _Float16 f16x8 __attribute__((ext_vector_type(8)));
typedef float f32x4 __attribute__((ext_vector_type(4)));

// ===================== atomic-free CSR build: 3-level MSD partition =====================
// record: [col:17 @47][row:17 @30][ew_f16 @0]   (col < 2^17 required; N=100000 ok)
constexpr int CHUNK = 4096;
constexpr int B1 = 64;
constexpr int B2 = 64;
constexpr int NC2 = 64;
constexpr int MAXC2 = 20;

__global__ __launch_bounds__(256) void k_p1hist(const int* __restrict__ col,
                                                int* __restrict__ cnt1, int E, int NB1)
{
    __shared__ int h[B1];
    int blk = blockIdx.x, t = threadIdx.x;
    if (t < B1) h[t] = 0;
    __syncthreads();
    int base = blk * CHUNK;
    for (int i = t; i < CHUNK; i += 256) {
        int g = base + i;
        if (g < E) atomicAdd(&h[col[g] >> 11], 1);
    }
    __syncthreads();
    if (t < B1) cnt1[t * NB1 + blk] = h[t];
}

__global__ __launch_bounds__(256) void k_blocksum(const int* __restrict__ cnt,
                                                  int* __restrict__ bsum, int n)
{
    __shared__ int s[256];
    int t = threadIdx.x;
    int i = blockIdx.x * 256 + t;
    s[t] = (i < n) ? cnt[i] : 0;
    __syncthreads();
    for (int o = 128; o > 0; o >>= 1) {
        if (t < o) s[t] += s[t + o];
        __syncthreads();
    }
    if (t == 0) bsum[blockIdx.x] = s[0];
}

__global__ __launch_bounds__(1024) void k_scan_bsum(const int* __restrict__ bsum,
                                                    int* __restrict__ boff, int nb,
                                                    int* __restrict__ out, int n, int total)
{
    __shared__ int s[1024];
    int t = threadIdx.x;
    int v = (t < nb) ? bsum[t] : 0;
    s[t] = v;
    __syncthreads();
    for (int o = 1; o < 1024; o <<= 1) {
        int u = (t >= o) ? s[t - o] : 0;
        __syncthreads();
        s[t] += u;
        __syncthreads();
    }
    if (t < nb) boff[t] = s[t] - v;   // exclusive
    if (t == 0) out[n] = total;
}

__global__ __launch_bounds__(256) void k_offsets(const int* __restrict__ cnt,
                                                 const int* __restrict__ boff,
                                                 int* __restrict__ out, int n)
{
    __shared__ int s[256];
    int t = threadIdx.x;
    int i = blockIdx.x * 256 + t;
    int v = (i < n) ? cnt[i] : 0;
    s[t] = v;
    __syncthreads();
    for (int o = 1; o < 256; o <<= 1) {
        int u = (t >= o) ? s[t - o] : 0;
        __syncthreads();
        s[t] += u;
        __syncthreads();
    }
    if (i < n) out[i] = boff[blockIdx.x] + s[t] - v;
}

__global__ __launch_bounds__(256) void k_p1part(const int* __restrict__ col,
                                                const int* __restrict__ row,
                                                const float* __restrict__ ew,
                                                const int* __restrict__ cnt1,
                                                const int* __restrict__ scan1,
                                                unsigned long long* __restrict__ rec1,
                                                int E, int NB1)
{
    __shared__ unsigned long long stage[CHUNK];
    __shared__ int hcnt[B1], lb[B1], gb[B1], cur[B1];
    int blk = blockIdx.x, t = threadIdx.x;
    if (t < B1) {
        hcnt[t] = cnt1[t * NB1 + blk];
        gb[t]   = scan1[t * NB1 + blk];
    }
    __syncthreads();
    if (t == 0) {
        int run = 0;
        for (int b = 0; b < B1; ++b) { lb[b] = run; run += hcnt[b]; }
    }
    __syncthreads();
    if (t < B1) cur[t] = lb[t];
    __syncthreads();
    int base = blk * CHUNK;
    for (int i = t; i < CHUNK; i += 256) {
        int g = base + i;
        if (g < E) {
            int c = col[g], r = row[g];
            unsigned long long rc = ((unsigned long long)c << 47) |
                                    ((unsigned long long)r << 30) |
                                    (unsigned long long)__half_as_ushort(__float2half(ew[g]));
            int p = atomicAdd(&cur[c >> 11], 1);
            stage[p] = rc;
        }
    }
    __syncthreads();
    int here = min(CHUNK, E - base);
    for (int j = t; j < here; j += 256) {
        unsigned long long rc = stage[j];
        int b = (int)(rc >> 58);
        rec1[gb[b] + (j - lb[b])] = rc;
    }
}

__global__ __launch_bounds__(256) void k_p2hist(const unsigned long long* __restrict__ rec1,
                                                const int* __restrict__ scan1,
                                                int* __restrict__ cnt2, int NB1)
{
    __shared__ int h[B2];
    int b = blockIdx.x / MAXC2, ci = blockIdx.x % MAXC2, t = threadIdx.x;
    int S1 = scan1[b * NB1];
    int S2 = scan1[(b + 1) * NB1];
    int size = S2 - S1;
    for (int c = ci; c * CHUNK < size && c < NC2; c += MAXC2) {
        __syncthreads();
        if (t < B2) h[t] = 0;
        __syncthreads();
        int cb = S1 + c * CHUNK, ce = min(cb + CHUNK, S2);
        for (int i = cb + t; i < ce; i += 256)
            atomicAdd(&h[(int)((rec1[i] >> 52) & 63)], 1);
        __syncthreads();
        if (t < B2) cnt2[(b * B2 + t) * NC2 + c] = h[t];
    }
}

__global__ __launch_bounds__(256) void k_p2part(const unsigned long long* __restrict__ rec1,
                                                const int* __restrict__ scan1,
                                                const int* __restrict__ cnt2,
                                                const int* __restrict__ scan2,
                                                unsigned long long* __restrict__ rec2, int NB1)
{
    __shared__ unsigned long long stage[CHUNK];
    __shared__ int hcnt[B2], lb[B2], gb[B2], cur[B2];
    int b = blockIdx.x / MAXC2, ci = blockIdx.x % MAXC2, t = threadIdx.x;
    int S1 = scan1[b * NB1];
    int S2 = scan1[(b + 1) * NB1];
    int size = S2 - S1;
    for (int c = ci; c * CHUNK < size && c < NC2; c += MAXC2) {
        __syncthreads();
        if (t < B2) {
            hcnt[t] = cnt2[(b * B2 + t) * NC2 + c];
            gb[t]   = scan2[(b * B2 + t) * NC2 + c];
        }
        __syncthreads();
        if (t == 0) {
            int run = 0;
            for (int sb = 0; sb < B2; ++sb) { lb[sb] = run; run += hcnt[sb]; }
        }
        __syncthreads();
        if (t < B2) cur[t] = lb[t];
        __syncthreads();
        int cb = S1 + c * CHUNK, ce = min(cb + CHUNK, S2);
        for (int i = cb + t; i < ce; i += 256) {
            unsigned long long rc = rec1[i];
            int p = atomicAdd(&cur[(int)((rc >> 52) & 63)], 1);
            stage[p] = rc;
        }
        __syncthreads();
        int here = ce - cb;
        for (int j = t; j < here; j += 256) {
            unsigned long long rc = stage[j];
            int sb = (int)((rc >> 52) & 63);
            rec2[gb[sb] + (j - lb[sb])] = rc;
        }
    }
}

// final: counting sort per 32-node sub-bucket.
// Bucket owns ALL edges of its 32 columns -> full weighted degree is local.
// Emits ep=(row, ew*dis[col]), off, dis.  (dis[col] folded into edge weight here;
// dis[row] is folded into the feature tables by k_cvt / mgemm epilogues.)
__global__ __launch_bounds__(256) void k_p3(const unsigned long long* __restrict__ rec2,
                                            const int* __restrict__ scan2,
                                            int2* __restrict__ ep, int* __restrict__ off,
                                            float* __restrict__ dis, int N, int E)
{
    __shared__ int h[32], lb[32], cur[32];
    __shared__ float dg[32], sdis[32];
    int g = blockIdx.x, t = threadIdx.x;
    int S1 = scan2[g * NC2];
    int S2 = scan2[(g + 1) * NC2];
    if (t < 32) { h[t] = 0; dg[t] = 0.f; }
    __syncthreads();
    for (int i = S1 + t; i < S2; i += 256) {
        unsigned long long rc = rec2[i];
        int nl = (int)((rc >> 47) & 31);
        atomicAdd(&h[nl], 1);
        atomicAdd(&dg[nl], __half2float(__ushort_as_half((unsigned short)(rc & 0xFFFF))));
    }
    __syncthreads();
    if (t == 0) {
        int run = S1;
        for (int k = 0; k < 32; ++k) { lb[k] = run; run += h[k]; }
    }
    __syncthreads();
    if (t < 32) {
        cur[t] = lb[t];
        sdis[t] = 1.0f / sqrtf(dg[t] + 1.0f);   // self-loop included; >= 1 always
        int node = g * 32 + t;
        if (node < N) { off[node] = lb[t]; dis[node] = sdis[t]; }
    }
    if (g == 0 && t == 0) off[N] = E;
    __syncthreads();
    for (int i = S1 + t; i < S2; i += 256) {
        unsigned long long rc = rec2[i];
        int nl = (int)((rc >> 47) & 31);
        int p = atomicAdd(&cur[nl], 1);
        float w = __half2float(__ushort_as_half((unsigned short)(rc & 0xFFFF))) * sdis[nl];
        ep[p] = make_int2((int)((rc >> 30) & 0x1FFFF), __float_as_int(w));
    }
}

// ---------------- f32 -> f16 convert with dis[row] pre-scale (stage A table) ----------------
__global__ __launch_bounds__(256) void k_cvt(const float4* __restrict__ in,
                                             const float* __restrict__ dis,
                                             __half2* __restrict__ out, int n4)
{
    int i = blockIdx.x * 256 + threadIdx.x;
    if (i >= n4) return;
    float4 v = in[i];
    float d = dis[i >> 5];          // 32 float4 per row
    __half2 a = __floats2half2_rn(v.x * d, v.y * d);
    __half2 b = __floats2half2_rn(v.z * d, v.w * d);
    float2 pk;
    ((__half2*)&pk)[0] = a;
    ((__half2*)&pk)[1] = b;
    *(float2*)&out[(size_t)i * 2] = pk;
}

// ---------------- W (f32 [128][N]) -> Wt (f16 [N][128]) transpose ----------------
__global__ __launch_bounds__(256) void k_wt(const float* __restrict__ W,
                                            __half* __restrict__ Wt, int N)
{
    int idx = blockIdx.x * 256 + threadIdx.x;
    if (idx >= N * 128) return;
    int n = idx >> 7, k = idx & 127;
    Wt[idx] = __float2half(W[(size_t)k * N + n]);
}

// ---------------- SpMM: Yh = fp16(aggregate of pre-scaled table) ----------------
// one wave per node; 4-wide batches, 2-deep pipeline (round-5 proven structure).
// Table rows pre-scaled by dis[row]; ep.y = ew*dis[col]; self weight = dis[node].
__global__ __launch_bounds__(256) void k_spmm(const __half2* __restrict__ Xh,
                                              const int2* __restrict__ ep,
                                              const int* __restrict__ off,
                                              const float* __restrict__ dis,
                                              __half2* __restrict__ Yh, int n)
{
    int gt = blockIdx.x * 256 + threadIdx.x;
    int node = gt >> 6;
    int lane = threadIdx.x & 63;
    if (node >= n) return;

    float sn = dis[node];                   // self weight (table already carries one dis)
    float2 x0 = __half22float2(Xh[(size_t)node * 64 + lane]);
    float a0x = sn * x0.x, a0y = sn * x0.y;
    float a1x = 0.f, a1y = 0.f;
    float a2x = 0.f, a2y = 0.f;
    float a3x = 0.f, a3y = 0.f;

    const int e0 = off[node];
    const int cnt = off[node + 1] - e0;
    const int2* el = ep + e0;
    const int nb = cnt >> 2;
    int done = 0;

    if (nb >= 2) {
        int2 q0, q1, q2, q3;
        int2 p0 = el[0], p1 = el[1], p2 = el[2], p3 = el[3];
        q0 = el[4]; q1 = el[5]; q2 = el[6]; q3 = el[7];
        __half2 xc0 = Xh[(size_t)p0.x * 64 + lane];
        __half2 xc1 = Xh[(size_t)p1.x * 64 + lane];
        __half2 xc2 = Xh[(size_t)p2.x * 64 + lane];
        __half2 xc3 = Xh[(size_t)p3.x * 64 + lane];
        float wc0 = __int_as_float(p0.y), wc1 = __int_as_float(p1.y);
        float wc2 = __int_as_float(p2.y), wc3 = __int_as_float(p3.y);

        int b;
        #pragma unroll 2
        for (b = 0; b + 2 < nb; ++b) {
            __half2 xn0 = Xh[(size_t)q0.x * 64 + lane];
            __half2 xn1 = Xh[(size_t)q1.x * 64 + lane];
            __half2 xn2 = Xh[(size_t)q2.x * 64 + lane];
            __half2 xn3 = Xh[(size_t)q3.x * 64 + lane];
            float wn0 = __int_as_float(q0.y), wn1 = __int_as_float(q1.y);
            float wn2 = __int_as_float(q2.y), wn3 = __int_as_float(q3.y);
            const int2* eb = el + (size_t)(b + 2) * 4;
            q0 = eb[0]; q1 = eb[1]; q2 = eb[2]; q3 = eb[3];
            float2 f0 = __half22float2(xc0), f1 = __half22float2(xc1);
            float2 f2 = __half22float2(xc2), f3 = __half22float2(xc3);
            a0x += wc0 * f0.x; a0y += wc0 * f0.y;
            a1x += wc1 * f1.x; a1y += wc1 * f1.y;
            a2x += wc2 * f2.x; a2y += wc2 * f2.y;
            a3x += wc3 * f3.x; a3y += wc3 * f3.y;
            xc0 = xn0; xc1 = xn1; xc2 = xn2; xc3 = xn3;
            wc0 = wn0; wc1 = wn1; wc2 = wn2; wc3 = wn3;
        }
        __half2 xn0 = Xh[(size_t)q0.x * 64 + lane];
        __half2 xn1 = Xh[(size_t)q1.x * 64 + lane];
        __half2 xn2 = Xh[(size_t)q2.x * 64 + lane];
        __half2 xn3 = Xh[(size_t)q3.x * 64 + lane];
        float wn0 = __int_as_float(q0.y), wn1 = __int_as_float(q1.y);
        float wn2 = __int_as_float(q2.y), wn3 = __int_as_float(q3.y);
        {
            float2 f0 = __half22float2(xc0), f1 = __half22float2(xc1);
            float2 f2 = __half22float2(xc2), f3 = __half22float2(xc3);
            a0x += wc0 * f0.x; a0y += wc0 * f0.y;
            a1x += wc1 * f1.x; a1y += wc1 * f1.y;
            a2x += wc2 * f2.x; a2y += wc2 * f2.y;
            a3x += wc3 * f3.x; a3y += wc3 * f3.y;
        }
        {
            float2 f0 = __half22float2(xn0), f1 = __half22float2(xn1);
            float2 f2 = __half22float2(xn2), f3 = __half22float2(xn3);
            a0x += wn0 * f0.x; a0y += wn0 * f0.y;
            a1x += wn1 * f1.x; a1y += wn1 * f1.y;
            a2x += wn2 * f2.x; a2y += wn2 * f2.y;
            a3x += wn3 * f3.x; a3y += wn3 * f3.y;
        }
        done = nb * 4;
    }
    for (int e = done; e < cnt; ++e) {
        int2 p = el[e];
        float2 xv = __half22float2(Xh[(size_t)p.x * 64 + lane]);
        float w = __int_as_float(p.y);
        a0x += w * xv.x; a0y += w * xv.y;
    }
    float rx = (a0x + a1x) + (a2x + a3x);
    float ry = (a0y + a1y) + (a2y + a3y);
    Yh[(size_t)node * 64 + lane] = __floats2half2_rn(rx, ry);
}

// ---------------- SpMM64 (stage C): aggregate 64-feature Zh, fused tanh+bias, fp32 out ----------------
// one wave per node, 1 feature per lane (2B gathers -> 128B/edge); writes d_out directly.
__global__ __launch_bounds__(256) void k_spmm64(const __half* __restrict__ Zh,
                                                const int2* __restrict__ ep,
                                                const int* __restrict__ off,
                                                const float* __restrict__ dis,
                                                const float* __restrict__ b6,
                                                float* __restrict__ out, int n)
{
    int gt = blockIdx.x * 256 + threadIdx.x;
    int node = gt >> 6;
    int lane = threadIdx.x & 63;
    if (node >= n) return;

    float sn = dis[node];
    float x0 = __half2float(Zh[(size_t)node * 64 + lane]);
    float a0 = sn * x0, a1 = 0.f, a2 = 0.f, a3 = 0.f;

    const int e0 = off[node];
    const int cnt = off[node + 1] - e0;
    const int2* el = ep + e0;
    const int nb = cnt >> 2;
    int done = 0;

    if (nb >= 2) {
        int2 q0, q1, q2, q3;
        int2 p0 = el[0], p1 = el[1], p2 = el[2], p3 = el[3];
        q0 = el[4]; q1 = el[5]; q2 = el[6]; q3 = el[7];
        __half xc0 = Zh[(size_t)p0.x * 64 + lane];
        __half xc1 = Zh[(size_t)p1.x * 64 + lane];
        __half xc2 = Zh[(size_t)p2.x * 64 + lane];
        __half xc3 = Zh[(size_t)p3.x * 64 + lane];
        float wc0 = __int_as_float(p0.y), wc1 = __int_as_float(p1.y);
        float wc2 = __int_as_float(p2.y), wc3 = __int_as_float(p3.y);

        int b;
        #pragma unroll 2
        for (b = 0; b + 2 < nb; ++b) {
            __half xn0 = Zh[(size_t)q0.x * 64 + lane];
            __half xn1 = Zh[(size_t)q1.x * 64 + lane];
            __half xn2 = Zh[(size_t)q2.x * 64 + lane];
            __half xn3 = Zh[(size_t)q3.x * 64 + lane];
            float wn0 = __int_as_float(q0.y), wn1 = __int_as_float(q1.y);
            float wn2 = __int_as_float(q2.y), wn3 = __int_as_float(q3.y);
            const int2* eb = el + (size_t)(b + 2) * 4;
            q0 = eb[0]; q1 = eb[1]; q2 = eb[2]; q3 = eb[3];
            a0 += wc0 * __half2float(xc0);
            a1 += wc1 * __half2float(xc1);
            a2 += wc2 * __half2float(xc2);
            a3 += wc3 * __half2float(xc3);
            xc0 = xn0; xc1 = xn1; xc2 = xn2; xc3 = xn3;
            wc0 = wn0; wc1 = wn1; wc2 = wn2; wc3 = wn3;
        }
        __half xn0 = Zh[(size_t)q0.x * 64 + lane];
        __half xn1 = Zh[(size_t)q1.x * 64 + lane];
        __half xn2 = Zh[(size_t)q2.x * 64 + lane];
        __half xn3 = Zh[(size_t)q3.x * 64 + lane];
        float wn0 = __int_as_float(q0.y), wn1 = __int_as_float(q1.y);
        float wn2 = __int_as_float(q2.y), wn3 = __int_as_float(q3.y);
        a0 += wc0 * __half2float(xc0);
        a1 += wc1 * __half2float(xc1);
        a2 += wc2 * __half2float(xc2);
        a3 += wc3 * __half2float(xc3);
        a0 += wn0 * __half2float(xn0);
        a1 += wn1 * __half2float(xn1);
        a2 += wn2 * __half2float(xn2);
        a3 += wn3 * __half2float(xn3);
        done = nb * 4;
    }
    for (int e = done; e < cnt; ++e) {
        int2 p = el[e];
        float w = __int_as_float(p.y);
        a0 += w * __half2float(Zh[(size_t)p.x * 64 + lane]);
    }
    float acc = (a0 + a1) + (a2 + a3);
    out[(size_t)node * 64 + lane] = tanhf(fmaf(acc, ZSCALE_COMP, b6[lane]));
}

// fast tanh: 1 - 2/(e^{2x}+1) via v_exp + v_rcp
__device__ __forceinline__ float fast_tanh(float x) {
    float e = __expf(2.0f * x);
    return 1.0f - 2.0f * __builtin_amdgcn_rcpf(e + 1.0f);
}

// ---------------- MFMA GEMM ----------------
// ACT=true : Out = fp16( OS * dis[row] * prod_w tanh(IS*(Yh W_w) + b_w) )
// ACT=false: Out = fp16( OS * (Yh W_0) )            (raw projection, no bias)
template <int FOUT, int NW, bool ACT>
__global__ __launch_bounds__(256, 4) void k_mgemm(const __half* __restrict__ Yh,
                                                  float IS, float OS,
                                                  const float* __restrict__ dis,
                                                  const __half* __restrict__ Wt0, const float* __restrict__ B0,
                                                  const __half* __restrict__ Wt1, const float* __restrict__ B1,
                                                  const __half* __restrict__ Wt2, const float* __restrict__ B2,
                                                  __half* __restrict__ Out, int nRows)
{
    constexpr int NF = FOUT / 16;
    int tid = threadIdx.x;
    int wv = tid >> 6;
    int lane = tid & 63;
    int lo = lane & 15, hi = lane >> 4;
    int r0 = blockIdx.x * 64 + wv * 16;

    f16x8 a[4];
    {
        int row = r0 + lo;
        if (row >= nRows) row = nRows - 1;
        const __half* Ap = Yh + (size_t)row * 128 + hi * 8;
        #pragma unroll
        for (int ks = 0; ks < 4; ++ks)
            a[ks] = *(const f16x8*)(Ap + ks * 32);
    }

    float disr[4];
    #pragma unroll
    for (int r = 0; r < 4; ++r) {
        int row = r0 + hi * 4 + r;
        if (row >= nRows) row = nRows - 1;
        disr[r] = ACT ? dis[row] : 1.0f;
    }

    const __half* Wts[3] = {Wt0, Wt1, Wt2};
    const float*  Bs[3]  = {B0, B1, B2};
    float prod[NF][4];

    #pragma unroll
    for (int w = 0; w < NW; ++w) {
        const __half* Wt = Wts[w] + (size_t)lo * 128 + hi * 8;
        const float*  Bb = Bs[w];
        #pragma unroll
        for (int f = 0; f < NF; ++f) {
            const __half* Bp = Wt + (size_t)f * 16 * 128;
            f32x4 acc = {0.f, 0.f, 0.f, 0.f};
            #pragma unroll
            for (int ks = 0; ks < 4; ++ks) {
                f16x8 bfrag = *(const f16x8*)(Bp + ks * 32);
                acc = __builtin_amdgcn_mfma_f32_16x16x32_f16(a[ks], bfrag, acc, 0, 0, 0);
            }
            if constexpr (ACT) {
                float bias = Bb[f * 16 + lo];
                #pragma unroll
                for (int r = 0; r < 4; ++r) {
                    float t = fast_tanh(fmaf(acc[r], IS, bias));
                    prod[f][r] = (w == 0) ? t : prod[f][r] * t;
                }
            } else {
                #pragma unroll
                for (int r = 0; r < 4; ++r) prod[f][r] = acc[r];
            }
        }
    }

    #pragma unroll
    for (int f = 0; f < NF; ++f) {
        int c = f * 16 + lo;
        #pragma unroll
        for (int r = 0; r < 4; ++r) {
            int row = r0 + hi * 4 + r;
            if (row < nRows)
                Out[(size_t)row * FOUT + c] = __float2half(prod[f][r] * (OS * disr[r]));
        }
    }
}

extern "C" void kernel_launch(void* const* d_in, const int* in_sizes, int n_in,
                              void* d_out, int out_size, void* d_ws, size_t ws_size,
                              hipStream_t stream)
{
    const float* h0 = (const float*)d_in[0];
    const int*   ei = (const int*)d_in[1];
    const float* ew = (const float*)d_in[2];
    const float* W1 = (const float*)d_in[3];  const float* b1 = (const float*)d_in[4];
    const float* W2 = (const float*)d_in[5];  const float* b2 = (const float*)d_in[6];
    const float* W3 = (const float*)d_in[7];  const float* b3 = (const float*)d_in[8];
    const float* W4 = (const float*)d_in[9];  const float* b4 = (const float*)d_in[10];
    const float* W5 = (const float*)d_in[11]; const float* b5 = (const float*)d_in[12];
    const float* W6 = (const float*)d_in[13]; const float* b6 = (const float*)d_in[14];

    const int N = in_sizes[0] / FDIM;
    const int E = in_sizes[2];
    const int* rowp = ei;
    const int* colp = ei + E;

    const int NB1 = (E + CHUNK - 1) / CHUNK;
    const int n1  = B1 * NB1;
    const int n2  = B1 * B2 * NC2;
    const int NBs1 = (n1 + 255) / 256;
    const int NBs2 = (n2 + 255) / 256;

    char* p = (char*)d_ws;
    auto alloc = [&](size_t bytes) -> void* {
        void* r = (void*)p;
        p += (bytes + 255) & ~(size_t)255;
        return r;
    };
    int* cnt1  = (int*)alloc((size_t)(n1 + 1) * 4);
    int* scan1 = (int*)alloc((size_t)(n1 + 1) * 4);
    int* cnt2  = (int*)alloc((size_t)(n2 + 1) * 4);
    int* scan2 = (int*)alloc((size_t)(n2 + 1) * 4);
    int* bsum  = (int*)alloc((size_t)1024 * 4);
    int* boff  = (int*)alloc((size_t)1024 * 4);
    int* off   = (int*)alloc((size_t)(N + 1) * 4);
    float* dis = (float*)alloc((size_t)N * 4);
    unsigned long long* rec1 = (unsigned long long*)alloc((size_t)E * 8);  // aliased by ep
    unsigned long long* rec2 = (unsigned long long*)alloc((size_t)E * 8);  // aliased by Yh
    __half2* Xh = (__half2*)alloc((size_t)N * FDIM * 2);                   // aliased by Zh
    __half2* Hh = (__half2*)alloc((size_t)N * FDIM * 2);
    __half* W1t = (__half*)alloc((size_t)128 * 128 * 2);
    __half* W2t = (__half*)alloc((size_t)128 * 128 * 2);
    __half* W3t = (__half*)alloc((size_t)128 * 128 * 2);
    __half* W4t = (__half*)alloc((size_t)128 * 128 * 2);
    __half* W5t = (__half*)alloc((size_t)128 * 128 * 2);
    __half* W6t = (__half*)alloc((size_t)64 * 128 * 2);

    int2*    ep = (int2*)rec1;       // rec1 dead after k_p2part
    __half2* Yh = (__half2*)rec2;    // rec2 dead after k_p3
    __half*  Zh = (__half*)Xh;       // Xh dead after stage-A spmm

    hipMemsetAsync(cnt2, 0, (size_t)(n2 + 1) * 4, stream);

    // ---- build (atomic-free, emits ep with dis[col] folded + dis[]) ----
    k_p1hist<<<NB1, 256, 0, stream>>>(colp, cnt1, E, NB1);
    k_blocksum<<<NBs1, 256, 0, stream>>>(cnt1, bsum, n1);
    k_scan_bsum<<<1, 1024, 0, stream>>>(bsum, boff, NBs1, scan1, n1, E);
    k_offsets<<<NBs1, 256, 0, stream>>>(cnt1, boff, scan1, n1);
    k_p1part<<<NB1, 256, 0, stream>>>(colp, rowp, ew, cnt1, scan1, rec1, E, NB1);
    k_p2hist<<<B1 * MAXC2, 256, 0, stream>>>(rec1, scan1, cnt2, NB1);
    k_blocksum<<<NBs2, 256, 0, stream>>>(cnt2, bsum, n2);
    k_scan_bsum<<<1, 1024, 0, stream>>>(bsum, boff, NBs2, scan2, n2, E);
    k_offsets<<<NBs2, 256, 0, stream>>>(cnt2, boff, scan2, n2);
    k_p2part<<<B1 * MAXC2, 256, 0, stream>>>(rec1, scan1, cnt2, scan2, rec2, NB1);
    k_p3<<<B1 * B2, 256, 0, stream>>>(rec2, scan2, ep, off, dis, N, E);

    // ---- dense prep (k_cvt needs dis) ----
    k_cvt<<<(N * 32 + 255) / 256, 256, 0, stream>>>((const float4*)h0, dis, Xh, N * 32);
    k_wt<<<64, 256, 0, stream>>>(W1, W1t, 128);
    k_wt<<<64, 256, 0, stream>>>(W2, W2t, 128);
    k_wt<<<64, 256, 0, stream>>>(W3, W3t, 128);
    k_wt<<<64, 256, 0, stream>>>(W4, W4t, 128);
    k_wt<<<64, 256, 0, stream>>>(W5, W5t, 128);
    k_wt<<<32, 256, 0, stream>>>(W6, W6t, 64);

    const int sb = (N + 3) / 4;     // 4 waves (nodes) per 256-thread block
    const int gb = (N + 63) / 64;   // 64-row tiles

    // Stage A: Yh = agg(Xh) ; Hh = HSCALE*dis*tanh(YhW1+b1)*tanh(YhW2+b2)*tanh(YhW3+b3)
    k_spmm<<<sb, 256, 0, stream>>>(Xh, ep, off, dis, Yh, N);
    k_mgemm<128, 3, true><<<gb, 256, 0, stream>>>((const __half*)Yh, 1.0f, HSCALE, dis,
        W1t, b1, W2t, b2, W3t, b3, (__half*)Hh, N);
    // Stage B: Yh = agg(Hh) = HSCALE*Ah123 ; Hh = HSCALE*dis*tanh(2^-14 YhW4+b4)*tanh(...)
    k_spmm<<<sb, 256, 0, stream>>>(Hh, ep, off, dis, Yh, N);
    k_mgemm<128, 2, true><<<gb, 256, 0, stream>>>((const __half*)Yh, HSCALE_INV, HSCALE, dis,
        W4t, b4, W5t, b5, nullptr, nullptr, (__half*)Hh, N);
    // Stage C: project first (Zh = ZSCALE * Hh W6 = ZSCALE*HSCALE*dis*h45W6, 64 features),
    //          then aggregate + fused tanh/bias -> d_out
    k_mgemm<64, 1, false><<<gb, 256, 0, stream>>>((const __half*)Hh, 1.0f, ZSCALE, nullptr,
        W6t, b6, nullptr, nullptr, nullptr, nullptr, Zh, N);
    k_spmm64<<<sb, 256, 0, stream>>>(Zh, ep, off, dis, b6, (float*)d_out, N);
}

// Round 8
// 518.735 us; speedup vs baseline: 1.3698x; 1.1700x over previous
//
#include <hip/hip_runtime.h>
#include <hip/hip_bf16.h>
#include <hip/hip_fp16.h>

constexpr int FDIM = 128;
#define HSCALE 16384.0f         // 2^14: |h|<1 -> scaled <16384 <= 65504, always safe
#define HSCALE_INV (1.0f/16384.0f)
#define ZSCALE 0.125f           // extra headroom for Zh = Hh @ W6
#define ZSCALE_COMP (HSCALE_INV * 8.0f)

typedef _Float16 f16x8 __attribute__((ext_vector_type(8)));
typedef float f32x4 __attribute__((ext_vector_type(4)));

// ===================== atomic-free CSR build: 3-level MSD partition =====================
// record: [col:17 @47][row:17 @30][ew_f16 @0]   (col < 2^17 required; N=100000 ok)
constexpr int CHUNK = 4096;
constexpr int B1 = 64;
constexpr int B2 = 64;
constexpr int NC2 = 64;
constexpr int MAXC2 = 20;

__global__ __launch_bounds__(256) void k_p1hist(const int* __restrict__ col,
                                                int* __restrict__ cnt1, int E, int NB1)
{
    __shared__ int h[B1];
    int blk = blockIdx.x, t = threadIdx.x;
    if (t < B1) h[t] = 0;
    __syncthreads();
    int base = blk * CHUNK;
    for (int i = t; i < CHUNK; i += 256) {
        int g = base + i;
        if (g < E) atomicAdd(&h[col[g] >> 11], 1);
    }
    __syncthreads();
    if (t < B1) cnt1[t * NB1 + blk] = h[t];
}

__global__ __launch_bounds__(256) void k_blocksum(const int* __restrict__ cnt,
                                                  int* __restrict__ bsum, int n)
{
    __shared__ int s[256];
    int t = threadIdx.x;
    int i = blockIdx.x * 256 + t;
    s[t] = (i < n) ? cnt[i] : 0;
    __syncthreads();
    for (int o = 128; o > 0; o >>= 1) {
        if (t < o) s[t] += s[t + o];
        __syncthreads();
    }
    if (t == 0) bsum[blockIdx.x] = s[0];
}

__global__ __launch_bounds__(1024) void k_scan_bsum(const int* __restrict__ bsum,
                                                    int* __restrict__ boff, int nb,
                                                    int* __restrict__ out, int n, int total)
{
    __shared__ int s[1024];
    int t = threadIdx.x;
    int v = (t < nb) ? bsum[t] : 0;
    s[t] = v;
    __syncthreads();
    for (int o = 1; o < 1024; o <<= 1) {
        int u = (t >= o) ? s[t - o] : 0;
        __syncthreads();
        s[t] += u;
        __syncthreads();
    }
    if (t < nb) boff[t] = s[t] - v;   // exclusive
    if (t == 0) out[n] = total;
}

__global__ __launch_bounds__(256) void k_offsets(const int* __restrict__ cnt,
                                                 const int* __restrict__ boff,
                                                 int* __restrict__ out, int n)
{
    __shared__ int s[256];
    int t = threadIdx.x;
    int i = blockIdx.x * 256 + t;
    int v = (i < n) ? cnt[i] : 0;
    s[t] = v;
    __syncthreads();
    for (int o = 1; o < 256; o <<= 1) {
        int u = (t >= o) ? s[t - o] : 0;
        __syncthreads();
        s[t] += u;
        __syncthreads();
    }
    if (i < n) out[i] = boff[blockIdx.x] + s[t] - v;
}

__global__ __launch_bounds__(256) void k_p1part(const int* __restrict__ col,
                                                const int* __restrict__ row,
                                                const float* __restrict__ ew,
                                                const int* __restrict__ cnt1,
                                                const int* __restrict__ scan1,
                                                unsigned long long* __restrict__ rec1,
                                                int E, int NB1)
{
    __shared__ unsigned long long stage[CHUNK];
    __shared__ int hcnt[B1], lb[B1], gb[B1], cur[B1];
    int blk = blockIdx.x, t = threadIdx.x;
    if (t < B1) {
        hcnt[t] = cnt1[t * NB1 + blk];
        gb[t]   = scan1[t * NB1 + blk];
    }
    __syncthreads();
    if (t == 0) {
        int run = 0;
        for (int b = 0; b < B1; ++b) { lb[b] = run; run += hcnt[b]; }
    }
    __syncthreads();
    if (t < B1) cur[t] = lb[t];
    __syncthreads();
    int base = blk * CHUNK;
    for (int i = t; i < CHUNK; i += 256) {
        int g = base + i;
        if (g < E) {
            int c = col[g], r = row[g];
            unsigned long long rc = ((unsigned long long)c << 47) |
                                    ((unsigned long long)r << 30) |
                                    (unsigned long long)__half_as_ushort(__float2half(ew[g]));
            int p = atomicAdd(&cur[c >> 11], 1);
            stage[p] = rc;
        }
    }
    __syncthreads();
    int here = min(CHUNK, E - base);
    for (int j = t; j < here; j += 256) {
        unsigned long long rc = stage[j];
        int b = (int)(rc >> 58);
        rec1[gb[b] + (j - lb[b])] = rc;
    }
}

__global__ __launch_bounds__(256) void k_p2hist(const unsigned long long* __restrict__ rec1,
                                                const int* __restrict__ scan1,
                                                int* __restrict__ cnt2, int NB1)
{
    __shared__ int h[B2];
    int b = blockIdx.x / MAXC2, ci = blockIdx.x % MAXC2, t = threadIdx.x;
    int S1 = scan1[b * NB1];
    int S2 = scan1[(b + 1) * NB1];
    int size = S2 - S1;
    for (int c = ci; c * CHUNK < size && c < NC2; c += MAXC2) {
        __syncthreads();
        if (t < B2) h[t] = 0;
        __syncthreads();
        int cb = S1 + c * CHUNK, ce = min(cb + CHUNK, S2);
        for (int i = cb + t; i < ce; i += 256)
            atomicAdd(&h[(int)((rec1[i] >> 52) & 63)], 1);
        __syncthreads();
        if (t < B2) cnt2[(b * B2 + t) * NC2 + c] = h[t];
    }
}

__global__ __launch_bounds__(256) void k_p2part(const unsigned long long* __restrict__ rec1,
                                                const int* __restrict__ scan1,
                                                const int* __restrict__ cnt2,
                                                const int* __restrict__ scan2,
                                                unsigned long long* __restrict__ rec2, int NB1)
{
    __shared__ unsigned long long stage[CHUNK];
    __shared__ int hcnt[B2], lb[B2], gb[B2], cur[B2];
    int b = blockIdx.x / MAXC2, ci = blockIdx.x % MAXC2, t = threadIdx.x;
    int S1 = scan1[b * NB1];
    int S2 = scan1[(b + 1) * NB1];
    int size = S2 - S1;
    for (int c = ci; c * CHUNK < size && c < NC2; c += MAXC2) {
        __syncthreads();
        if (t < B2) {
            hcnt[t] = cnt2[(b * B2 + t) * NC2 + c];
            gb[t]   = scan2[(b * B2 + t) * NC2 + c];
        }
        __syncthreads();
        if (t == 0) {
            int run = 0;
            for (int sb = 0; sb < B2; ++sb) { lb[sb] = run; run += hcnt[sb]; }
        }
        __syncthreads();
        if (t < B2) cur[t] = lb[t];
        __syncthreads();
        int cb = S1 + c * CHUNK, ce = min(cb + CHUNK, S2);
        for (int i = cb + t; i < ce; i += 256) {
            unsigned long long rc = rec1[i];
            int p = atomicAdd(&cur[(int)((rc >> 52) & 63)], 1);
            stage[p] = rc;
        }
        __syncthreads();
        int here = ce - cb;
        for (int j = t; j < here; j += 256) {
            unsigned long long rc = stage[j];
            int sb = (int)((rc >> 52) & 63);
            rec2[gb[sb] + (j - lb[sb])] = rc;
        }
    }
}

// final: counting sort per 32-node sub-bucket.
// Bucket owns ALL edges of its 32 columns -> full weighted degree is local.
// Emits ep=(row, ew*dis[col]), off, dis.
__global__ __launch_bounds__(256) void k_p3(const unsigned long long* __restrict__ rec2,
                                            const int* __restrict__ scan2,
                                            int2* __restrict__ ep, int* __restrict__ off,
                                            float* __restrict__ dis, int N, int E)
{
    __shared__ int h[32], lb[32], cur[32];
    __shared__ float dg[32], sdis[32];
    int g = blockIdx.x, t = threadIdx.x;
    int S1 = scan2[g * NC2];
    int S2 = scan2[(g + 1) * NC2];
    if (t < 32) { h[t] = 0; dg[t] = 0.f; }
    __syncthreads();
    for (int i = S1 + t; i < S2; i += 256) {
        unsigned long long rc = rec2[i];
        int nl = (int)((rc >> 47) & 31);
        atomicAdd(&h[nl], 1);
        atomicAdd(&dg[nl], __half2float(__ushort_as_half((unsigned short)(rc & 0xFFFF))));
    }
    __syncthreads();
    if (t == 0) {
        int run = S1;
        for (int k = 0; k < 32; ++k) { lb[k] = run; run += h[k]; }
    }
    __syncthreads();
    if (t < 32) {
        cur[t] = lb[t];
        sdis[t] = 1.0f / sqrtf(dg[t] + 1.0f);   // self-loop included; >= 1 always
        int node = g * 32 + t;
        if (node < N) { off[node] = lb[t]; dis[node] = sdis[t]; }
    }
    if (g == 0 && t == 0) off[N] = E;
    __syncthreads();
    for (int i = S1 + t; i < S2; i += 256) {
        unsigned long long rc = rec2[i];
        int nl = (int)((rc >> 47) & 31);
        int p = atomicAdd(&cur[nl], 1);
        float w = __half2float(__ushort_as_half((unsigned short)(rc & 0xFFFF))) * sdis[nl];
        ep[p] = make_int2((int)((rc >> 30) & 0x1FFFF), __float_as_int(w));
    }
}

// ---------------- f32 -> f16 convert with dis[row] pre-scale (stage A table) ----------------
__global__ __launch_bounds__(256) void k_cvt(const float4* __restrict__ in,
                                             const float* __restrict__ dis,
                                             __half2* __restrict__ out, int n4)
{
    int i = blockIdx.x * 256 + threadIdx.x;
    if (i >= n4) return;
    float4 v = in[i];
    float d = dis[i >> 5];          // 32 float4 per row
    __half2 a = __floats2half2_rn(v.x * d, v.y * d);
    __half2 b = __floats2half2_rn(v.z * d, v.w * d);
    float2 pk;
    ((__half2*)&pk)[0] = a;
    ((__half2*)&pk)[1] = b;
    *(float2*)&out[(size_t)i * 2] = pk;
}

// ---------------- W (f32 [128][N]) -> Wt (f16 [N][128]) transpose ----------------
__global__ __launch_bounds__(256) void k_wt(const float* __restrict__ W,
                                            __half* __restrict__ Wt, int N)
{
    int idx = blockIdx.x * 256 + threadIdx.x;
    if (idx >= N * 128) return;
    int n = idx >> 7, k = idx & 127;
    Wt[idx] = __float2half(W[(size_t)k * N + n]);
}

// ---------------- SpMM: Yh = fp16(aggregate of pre-scaled table) ----------------
// one wave per node; 4-wide batches, 2-deep pipeline (round-5 proven structure).
__global__ __launch_bounds__(256) void k_spmm(const __half2* __restrict__ Xh,
                                              const int2* __restrict__ ep,
                                              const int* __restrict__ off,
                                              const float* __restrict__ dis,
                                              __half2* __restrict__ Yh, int n)
{
    int gt = blockIdx.x * 256 + threadIdx.x;
    int node = gt >> 6;
    int lane = threadIdx.x & 63;
    if (node >= n) return;

    float sn = dis[node];                   // self weight (table already carries one dis)
    float2 x0 = __half22float2(Xh[(size_t)node * 64 + lane]);
    float a0x = sn * x0.x, a0y = sn * x0.y;
    float a1x = 0.f, a1y = 0.f;
    float a2x = 0.f, a2y = 0.f;
    float a3x = 0.f, a3y = 0.f;

    const int e0 = off[node];
    const int cnt = off[node + 1] - e0;
    const int2* el = ep + e0;
    const int nb = cnt >> 2;
    int done = 0;

    if (nb >= 2) {
        int2 q0, q1, q2, q3;
        int2 p0 = el[0], p1 = el[1], p2 = el[2], p3 = el[3];
        q0 = el[4]; q1 = el[5]; q2 = el[6]; q3 = el[7];
        __half2 xc0 = Xh[(size_t)p0.x * 64 + lane];
        __half2 xc1 = Xh[(size_t)p1.x * 64 + lane];
        __half2 xc2 = Xh[(size_t)p2.x * 64 + lane];
        __half2 xc3 = Xh[(size_t)p3.x * 64 + lane];
        float wc0 = __int_as_float(p0.y), wc1 = __int_as_float(p1.y);
        float wc2 = __int_as_float(p2.y), wc3 = __int_as_float(p3.y);

        int b;
        #pragma unroll 2
        for (b = 0; b + 2 < nb; ++b) {
            __half2 xn0 = Xh[(size_t)q0.x * 64 + lane];
            __half2 xn1 = Xh[(size_t)q1.x * 64 + lane];
            __half2 xn2 = Xh[(size_t)q2.x * 64 + lane];
            __half2 xn3 = Xh[(size_t)q3.x * 64 + lane];
            float wn0 = __int_as_float(q0.y), wn1 = __int_as_float(q1.y);
            float wn2 = __int_as_float(q2.y), wn3 = __int_as_float(q3.y);
            const int2* eb = el + (size_t)(b + 2) * 4;
            q0 = eb[0]; q1 = eb[1]; q2 = eb[2]; q3 = eb[3];
            float2 f0 = __half22float2(xc0), f1 = __half22float2(xc1);
            float2 f2 = __half22float2(xc2), f3 = __half22float2(xc3);
            a0x += wc0 * f0.x; a0y += wc0 * f0.y;
            a1x += wc1 * f1.x; a1y += wc1 * f1.y;
            a2x += wc2 * f2.x; a2y += wc2 * f2.y;
            a3x += wc3 * f3.x; a3y += wc3 * f3.y;
            xc0 = xn0; xc1 = xn1; xc2 = xn2; xc3 = xn3;
            wc0 = wn0; wc1 = wn1; wc2 = wn2; wc3 = wn3;
        }
        __half2 xn0 = Xh[(size_t)q0.x * 64 + lane];
        __half2 xn1 = Xh[(size_t)q1.x * 64 + lane];
        __half2 xn2 = Xh[(size_t)q2.x * 64 + lane];
        __half2 xn3 = Xh[(size_t)q3.x * 64 + lane];
        float wn0 = __int_as_float(q0.y), wn1 = __int_as_float(q1.y);
        float wn2 = __int_as_float(q2.y), wn3 = __int_as_float(q3.y);
        {
            float2 f0 = __half22float2(xc0), f1 = __half22float2(xc1);
            float2 f2 = __half22float2(xc2), f3 = __half22float2(xc3);
            a0x += wc0 * f0.x; a0y += wc0 * f0.y;
            a1x += wc1 * f1.x; a1y += wc1 * f1.y;
            a2x += wc2 * f2.x; a2y += wc2 * f2.y;
            a3x += wc3 * f3.x; a3y += wc3 * f3.y;
        }
        {
            float2 f0 = __half22float2(xn0), f1 = __half22float2(xn1);
            float2 f2 = __half22float2(xn2), f3 = __half22float2(xn3);
            a0x += wn0 * f0.x; a0y += wn0 * f0.y;
            a1x += wn1 * f1.x; a1y += wn1 * f1.y;
            a2x += wn2 * f2.x; a2y += wn2 * f2.y;
            a3x += wn3 * f3.x; a3y += wn3 * f3.y;
        }
        done = nb * 4;
    }
    for (int e = done; e < cnt; ++e) {
        int2 p = el[e];
        float2 xv = __half22float2(Xh[(size_t)p.x * 64 + lane]);
        float w = __int_as_float(p.y);
        a0x += w * xv.x; a0y += w * xv.y;
    }
    float rx = (a0x + a1x) + (a2x + a3x);
    float ry = (a0y + a1y) + (a2y + a3y);
    Yh[(size_t)node * 64 + lane] = __floats2half2_rn(rx, ry);
}

// ---------------- SpMM64 (stage C): aggregate 64-feature Zh, fused tanh+bias, fp32 out ----------------
__global__ __launch_bounds__(256) void k_spmm64(const __half* __restrict__ Zh,
                                                const int2* __restrict__ ep,
                                                const int* __restrict__ off,
                                                const float* __restrict__ dis,
                                                const float* __restrict__ b6,
                                                float* __restrict__ out, int n)
{
    int gt = blockIdx.x * 256 + threadIdx.x;
    int node = gt >> 6;
    int lane = threadIdx.x & 63;
    if (node >= n) return;

    float sn = dis[node];
    float x0 = __half2float(Zh[(size_t)node * 64 + lane]);
    float a0 = sn * x0, a1 = 0.f, a2 = 0.f, a3 = 0.f;

    const int e0 = off[node];
    const int cnt = off[node + 1] - e0;
    const int2* el = ep + e0;
    const int nb = cnt >> 2;
    int done = 0;

    if (nb >= 2) {
        int2 q0, q1, q2, q3;
        int2 p0 = el[0], p1 = el[1], p2 = el[2], p3 = el[3];
        q0 = el[4]; q1 = el[5]; q2 = el[6]; q3 = el[7];
        __half xc0 = Zh[(size_t)p0.x * 64 + lane];
        __half xc1 = Zh[(size_t)p1.x * 64 + lane];
        __half xc2 = Zh[(size_t)p2.x * 64 + lane];
        __half xc3 = Zh[(size_t)p3.x * 64 + lane];
        float wc0 = __int_as_float(p0.y), wc1 = __int_as_float(p1.y);
        float wc2 = __int_as_float(p2.y), wc3 = __int_as_float(p3.y);

        int b;
        #pragma unroll 2
        for (b = 0; b + 2 < nb; ++b) {
            __half xn0 = Zh[(size_t)q0.x * 64 + lane];
            __half xn1 = Zh[(size_t)q1.x * 64 + lane];
            __half xn2 = Zh[(size_t)q2.x * 64 + lane];
            __half xn3 = Zh[(size_t)q3.x * 64 + lane];
            float wn0 = __int_as_float(q0.y), wn1 = __int_as_float(q1.y);
            float wn2 = __int_as_float(q2.y), wn3 = __int_as_float(q3.y);
            const int2* eb = el + (size_t)(b + 2) * 4;
            q0 = eb[0]; q1 = eb[1]; q2 = eb[2]; q3 = eb[3];
            a0 += wc0 * __half2float(xc0);
            a1 += wc1 * __half2float(xc1);
            a2 += wc2 * __half2float(xc2);
            a3 += wc3 * __half2float(xc3);
            xc0 = xn0; xc1 = xn1; xc2 = xn2; xc3 = xn3;
            wc0 = wn0; wc1 = wn1; wc2 = wn2; wc3 = wn3;
        }
        __half xn0 = Zh[(size_t)q0.x * 64 + lane];
        __half xn1 = Zh[(size_t)q1.x * 64 + lane];
        __half xn2 = Zh[(size_t)q2.x * 64 + lane];
        __half xn3 = Zh[(size_t)q3.x * 64 + lane];
        float wn0 = __int_as_float(q0.y), wn1 = __int_as_float(q1.y);
        float wn2 = __int_as_float(q2.y), wn3 = __int_as_float(q3.y);
        a0 += wc0 * __half2float(xc0);
        a1 += wc1 * __half2float(xc1);
        a2 += wc2 * __half2float(xc2);
        a3 += wc3 * __half2float(xc3);
        a0 += wn0 * __half2float(xn0);
        a1 += wn1 * __half2float(xn1);
        a2 += wn2 * __half2float(xn2);
        a3 += wn3 * __half2float(xn3);
        done = nb * 4;
    }
    for (int e = done; e < cnt; ++e) {
        int2 p = el[e];
        float w = __int_as_float(p.y);
        a0 += w * __half2float(Zh[(size_t)p.x * 64 + lane]);
    }
    float acc = (a0 + a1) + (a2 + a3);
    out[(size_t)node * 64 + lane] = tanhf(fmaf(acc, ZSCALE_COMP, b6[lane]));
}

// fast tanh: 1 - 2/(e^{2x}+1) via v_exp + v_rcp
__device__ __forceinline__ float fast_tanh(float x) {
    float e = __expf(2.0f * x);
    return 1.0f - 2.0f * __builtin_amdgcn_rcpf(e + 1.0f);
}

// ---------------- MFMA GEMM, register-resident B ----------------
// Block = 256 threads = 4 waves, 64 rows. Wave wv owns cols [wv*FPW*16, ...):
// B-frags for its FPW col-fragments x NW weights x 4 k-slices live in VGPRs for
// the whole block (~24 frags = 96 VGPR at FOUT=128/NW=3). A streams from global
// per 16-row subtile with 1-deep prefetch. All MFMA register-fed; no LDS.
// ACT=true : Out = fp16( OS * dis[row] * prod_w tanh(IS*(Yh W_w) + b_w) )
// ACT=false: Out = fp16( OS * (Yh W_0) )
template <int FOUT, int NW, bool ACT>
__global__ __launch_bounds__(256, 2) void k_mgemm(const __half* __restrict__ Yh,
                                                  float IS, float OS,
                                                  const float* __restrict__ dis,
                                                  const __half* __restrict__ Wt0, const float* __restrict__ B0,
                                                  const __half* __restrict__ Wt1, const float* __restrict__ B1,
                                                  const __half* __restrict__ Wt2, const float* __restrict__ B2,
                                                  __half* __restrict__ Out, int nRows)
{
    constexpr int NF = FOUT / 16;
    constexpr int FPW = NF / 4;     // col-fragments per wave: 2 (FOUT=128) or 1 (FOUT=64)
    int tid = threadIdx.x;
    int wv = tid >> 6;
    int lane = tid & 63;
    int lo = lane & 15, hi = lane >> 4;
    int r0 = blockIdx.x * 64;

    const __half* Wts[3] = {Wt0, Wt1, Wt2};
    const float*  Bs[3]  = {B0, B1, B2};

    // B-fragments: loaded once, register-resident for the whole block
    f16x8 bfr[FPW][NW][4];
    float bias[FPW][NW];
    #pragma unroll
    for (int fp = 0; fp < FPW; ++fp) {
        int f = wv * FPW + fp;
        #pragma unroll
        for (int w = 0; w < NW; ++w) {
            const __half* Bp = Wts[w] + (size_t)(f * 16 + lo) * 128 + hi * 8;
            #pragma unroll
            for (int ks = 0; ks < 4; ++ks)
                bfr[fp][w][ks] = *(const f16x8*)(Bp + ks * 32);
            if constexpr (ACT) bias[fp][w] = Bs[w][f * 16 + lo];
        }
    }

    // dis for this wave's 64 output rows (4 subtiles x 4 regs), C/D row mapping
    float disr[4][4];
    if constexpr (ACT) {
        #pragma unroll
        for (int rt = 0; rt < 4; ++rt)
            #pragma unroll
            for (int r = 0; r < 4; ++r) {
                int row = r0 + rt * 16 + hi * 4 + r;
                if (row >= nRows) row = nRows - 1;
                disr[rt][r] = dis[row];
            }
    }

    // A subtile prefetch pipeline
    f16x8 a[4], an[4];
    {
        int row = r0 + lo;
        if (row >= nRows) row = nRows - 1;
        const __half* Ap = Yh + (size_t)row * 128 + hi * 8;
        #pragma unroll
        for (int ks = 0; ks < 4; ++ks) a[ks] = *(const f16x8*)(Ap + ks * 32);
    }

    #pragma unroll
    for (int rt = 0; rt < 4; ++rt) {
        if (rt < 3) {
            int row = r0 + (rt + 1) * 16 + lo;
            if (row >= nRows) row = nRows - 1;
            const __half* Ap = Yh + (size_t)row * 128 + hi * 8;
            #pragma unroll
            for (int ks = 0; ks < 4; ++ks) an[ks] = *(const f16x8*)(Ap + ks * 32);
        }
        #pragma unroll
        for (int fp = 0; fp < FPW; ++fp) {
            f32x4 ac0 = {0.f, 0.f, 0.f, 0.f};
            f32x4 ac1 = {0.f, 0.f, 0.f, 0.f};
            f32x4 ac2 = {0.f, 0.f, 0.f, 0.f};
            #pragma unroll
            for (int ks = 0; ks < 4; ++ks) {
                ac0 = __builtin_amdgcn_mfma_f32_16x16x32_f16(a[ks], bfr[fp][0][ks], ac0, 0, 0, 0);
                if constexpr (NW > 1)
                    ac1 = __builtin_amdgcn_mfma_f32_16x16x32_f16(a[ks], bfr[fp][1][ks], ac1, 0, 0, 0);
                if constexpr (NW > 2)
                    ac2 = __builtin_amdgcn_mfma_f32_16x16x32_f16(a[ks], bfr[fp][2][ks], ac2, 0, 0, 0);
            }
            int c = (wv * FPW + fp) * 16 + lo;
            #pragma unroll
            for (int r = 0; r < 4; ++r) {
                int row = r0 + rt * 16 + hi * 4 + r;
                float v;
                if constexpr (ACT) {
                    v = fast_tanh(fmaf(ac0[r], IS, bias[fp][0]));
                    if constexpr (NW > 1) v *= fast_tanh(fmaf(ac1[r], IS, bias[fp][1]));
                    if constexpr (NW > 2) v *= fast_tanh(fmaf(ac2[r], IS, bias[fp][2]));
                    v *= OS * disr[rt][r];
                } else {
                    v = ac0[r] * OS;
                }
                if (row < nRows)
                    Out[(size_t)row * FOUT + c] = __float2half(v);
            }
        }
        #pragma unroll
        for (int ks = 0; ks < 4; ++ks) a[ks] = an[ks];
    }
}

extern "C" void kernel_launch(void* const* d_in, const int* in_sizes, int n_in,
                              void* d_out, int out_size, void* d_ws, size_t ws_size,
                              hipStream_t stream)
{
    const float* h0 = (const float*)d_in[0];
    const int*   ei = (const int*)d_in[1];
    const float* ew = (const float*)d_in[2];
    const float* W1 = (const float*)d_in[3];  const float* b1 = (const float*)d_in[4];
    const float* W2 = (const float*)d_in[5];  const float* b2 = (const float*)d_in[6];
    const float* W3 = (const float*)d_in[7];  const float* b3 = (const float*)d_in[8];
    const float* W4 = (const float*)d_in[9];  const float* b4 = (const float*)d_in[10];
    const float* W5 = (const float*)d_in[11]; const float* b5 = (const float*)d_in[12];
    const float* W6 = (const float*)d_in[13]; const float* b6 = (const float*)d_in[14];

    const int N = in_sizes[0] / FDIM;
    const int E = in_sizes[2];
    const int* rowp = ei;
    const int* colp = ei + E;

    const int NB1 = (E + CHUNK - 1) / CHUNK;
    const int n1  = B1 * NB1;
    const int n2  = B1 * B2 * NC2;
    const int NBs1 = (n1 + 255) / 256;
    const int NBs2 = (n2 + 255) / 256;

    char* p = (char*)d_ws;
    auto alloc = [&](size_t bytes) -> void* {
        void* r = (void*)p;
        p += (bytes + 255) & ~(size_t)255;
        return r;
    };
    int* cnt1  = (int*)alloc((size_t)(n1 + 1) * 4);
    int* scan1 = (int*)alloc((size_t)(n1 + 1) * 4);
    int* cnt2  = (int*)alloc((size_t)(n2 + 1) * 4);
    int* scan2 = (int*)alloc((size_t)(n2 + 1) * 4);
    int* bsum  = (int*)alloc((size_t)1024 * 4);
    int* boff  = (int*)alloc((size_t)1024 * 4);
    int* off   = (int*)alloc((size_t)(N + 1) * 4);
    float* dis = (float*)alloc((size_t)N * 4);
    unsigned long long* rec1 = (unsigned long long*)alloc((size_t)E * 8);  // aliased by ep
    unsigned long long* rec2 = (unsigned long long*)alloc((size_t)E * 8);  // aliased by Yh
    __half2* Xh = (__half2*)alloc((size_t)N * FDIM * 2);                   // aliased by Zh
    __half2* Hh = (__half2*)alloc((size_t)N * FDIM * 2);
    __half* W1t = (__half*)alloc((size_t)128 * 128 * 2);
    __half* W2t = (__half*)alloc((size_t)128 * 128 * 2);
    __half* W3t = (__half*)alloc((size_t)128 * 128 * 2);
    __half* W4t = (__half*)alloc((size_t)128 * 128 * 2);
    __half* W5t = (__half*)alloc((size_t)128 * 128 * 2);
    __half* W6t = (__half*)alloc((size_t)64 * 128 * 2);

    int2*    ep = (int2*)rec1;       // rec1 dead after k_p2part
    __half2* Yh = (__half2*)rec2;    // rec2 dead after k_p3
    __half*  Zh = (__half*)Xh;       // Xh dead after stage-A spmm

    hipMemsetAsync(cnt2, 0, (size_t)(n2 + 1) * 4, stream);

    // ---- build (atomic-free, emits ep with dis[col] folded + dis[]) ----
    k_p1hist<<<NB1, 256, 0, stream>>>(colp, cnt1, E, NB1);
    k_blocksum<<<NBs1, 256, 0, stream>>>(cnt1, bsum, n1);
    k_scan_bsum<<<1, 1024, 0, stream>>>(bsum, boff, NBs1, scan1, n1, E);
    k_offsets<<<NBs1, 256, 0, stream>>>(cnt1, boff, scan1, n1);
    k_p1part<<<NB1, 256, 0, stream>>>(colp, rowp, ew, cnt1, scan1, rec1, E, NB1);
    k_p2hist<<<B1 * MAXC2, 256, 0, stream>>>(rec1, scan1, cnt2, NB1);
    k_blocksum<<<NBs2, 256, 0, stream>>>(cnt2, bsum, n2);
    k_scan_bsum<<<1, 1024, 0, stream>>>(bsum, boff, NBs2, scan2, n2, E);
    k_offsets<<<NBs2, 256, 0, stream>>>(cnt2, boff, scan2, n2);
    k_p2part<<<B1 * MAXC2, 256, 0, stream>>>(rec1, scan1, cnt2, scan2, rec2, NB1);
    k_p3<<<B1 * B2, 256, 0, stream>>>(rec2, scan2, ep, off, dis, N, E);

    // ---- dense prep (k_cvt needs dis) ----
    k_cvt<<<(N * 32 + 255) / 256, 256, 0, stream>>>((const float4*)h0, dis, Xh, N * 32);
    k_wt<<<64, 256, 0, stream>>>(W1, W1t, 128);
    k_wt<<<64, 256, 0, stream>>>(W2, W2t, 128);
    k_wt<<<64, 256, 0, stream>>>(W3, W3t, 128);
    k_wt<<<64, 256, 0, stream>>>(W4, W4t, 128);
    k_wt<<<64, 256, 0, stream>>>(W5, W5t, 128);
    k_wt<<<32, 256, 0, stream>>>(W6, W6t, 64);

    const int sb = (N + 3) / 4;     // 4 waves (nodes) per 256-thread block
    const int gb = (N + 63) / 64;   // 64-row tiles

    // Stage A: Yh = agg(Xh) ; Hh = HSCALE*dis*tanh(YhW1+b1)*tanh(YhW2+b2)*tanh(YhW3+b3)
    k_spmm<<<sb, 256, 0, stream>>>(Xh, ep, off, dis, Yh, N);
    k_mgemm<128, 3, true><<<gb, 256, 0, stream>>>((const __half*)Yh, 1.0f, HSCALE, dis,
        W1t, b1, W2t, b2, W3t, b3, (__half*)Hh, N);
    // Stage B: Yh = agg(Hh) ; Hh = HSCALE*dis*tanh(2^-14 YhW4+b4)*tanh(2^-14 YhW5+b5)
    k_spmm<<<sb, 256, 0, stream>>>(Hh, ep, off, dis, Yh, N);
    k_mgemm<128, 2, true><<<gb, 256, 0, stream>>>((const __half*)Yh, HSCALE_INV, HSCALE, dis,
        W4t, b4, W5t, b5, nullptr, nullptr, (__half*)Hh, N);
    // Stage C: project first (Zh = ZSCALE * Hh W6, 64 features), then aggregate+tanh -> out
    k_mgemm<64, 1, false><<<gb, 256, 0, stream>>>((const __half*)Hh, 1.0f, ZSCALE, nullptr,
        W6t, b6, nullptr, nullptr, nullptr, nullptr, Zh, N);
    k_spmm64<<<sb, 256, 0, stream>>>(Zh, ep, off, dis, b6, (float*)d_out, N);
}